// Round 1
// baseline (36894.073 us; speedup 1.0000x reference)
//
#include <hip/hip_runtime.h>
#include <cstddef>

#define BB 128
#define TT 512
#define II 64
#define HH 256

// ---------- cross-lane helpers ----------
template<int CTRL>
__device__ __forceinline__ float dpp_add(float x) {
    int p = __builtin_amdgcn_update_dpp(0, __float_as_int(x), CTRL, 0xF, 0xF, true);
    return x + __int_as_float(p);
}

// Sum over 8-lane groups (q = lane & 7). Result valid in ALL lanes of the group.
// Stages 1-2: quad_perm butterflies (full-rate VALU DPP). Stage 3: ds_swizzle xor-4
// (direction-proof; candidate to replace with row_shl:4 DPP in a later round).
__device__ __forceinline__ float red8(float x) {
    x = dpp_add<0xB1>(x);   // quad_perm [1,0,3,2]  -> + lane^1
    x = dpp_add<0x4E>(x);   // quad_perm [2,3,0,1]  -> + lane^2
    int y = __builtin_amdgcn_ds_swizzle(__float_as_int(x), 0x101F); // xor 4, and=0x1F
    return x + __int_as_float(y);
}

__device__ __forceinline__ float sigf(float x) {
    return 1.0f / (1.0f + __expf(-x));
}
__device__ __forceinline__ float tanh_fast(float x) {
    x = fminf(15.0f, fmaxf(-15.0f, x));   // avoid inf/inf
    float e = __expf(2.0f * x);
    return (e - 1.0f) / (e + 1.0f);
}

// ---------- fused GRU layer: one block per batch element, weights in registers ----------
// Thread (u = tid>>3, q = tid&7) owns hidden units {2u, 2u+1}:
//   W_hh rows {j, 256+j, 512+j} cols [32q, 32q+32)  -> 192 regs
//   W_ih rows same, cols [XC*q, XC*q+XC)            -> 48 (L0) / 192 (L1) regs
// Per step: partial dots -> 8-lane reduce -> gate math on q==0 lanes.
// h and x_t staged in LDS with a 16B-granule XOR swizzle (g ^ g>>3) so the
// 128B-strided float4 reads are bank-conflict-free.
template<int KIN, bool STORE_ALL>
__global__ __launch_bounds__(1024) void gru_layer_kernel(
    const float* __restrict__ xg,     // [B, T, KIN]
    const float* __restrict__ W_ih,   // [768, KIN]
    const float* __restrict__ W_hh,   // [768, 256]
    const float* __restrict__ b_ih,   // [768]
    const float* __restrict__ b_hh,   // [768]
    float* __restrict__ hout)         // STORE_ALL ? [B,T,256] : [B,256]
{
    constexpr int XC  = KIN / 8;      // x columns per thread
    constexpr int XG4 = XC / 4;       // float4 chunks of those

    const int b   = blockIdx.x;
    const int tid = threadIdx.x;
    const int q   = tid & 7;
    const int u   = tid >> 3;         // 0..127
    const int j0  = 2 * u;

    __shared__ float hs[HH];
    __shared__ float xs[KIN];

    // ---- load weights into registers (one-time) ----
    float whh[2][3][32];
    float wih[2][3][XC];
    #pragma unroll
    for (int s = 0; s < 2; ++s) {
        #pragma unroll
        for (int g = 0; g < 3; ++g) {
            const int row = g * HH + j0 + s;
            const float4* wr = (const float4*)(W_hh + (size_t)row * HH + 32 * q);
            #pragma unroll
            for (int k4 = 0; k4 < 8; ++k4) {
                float4 v = wr[k4];
                whh[s][g][4*k4+0] = v.x; whh[s][g][4*k4+1] = v.y;
                whh[s][g][4*k4+2] = v.z; whh[s][g][4*k4+3] = v.w;
            }
            const float4* wr2 = (const float4*)(W_ih + (size_t)row * KIN + XC * q);
            #pragma unroll
            for (int k4 = 0; k4 < XG4; ++k4) {
                float4 v = wr2[k4];
                wih[s][g][4*k4+0] = v.x; wih[s][g][4*k4+1] = v.y;
                wih[s][g][4*k4+2] = v.z; wih[s][g][4*k4+3] = v.w;
            }
        }
    }

    // biases (used only by q==0 lanes)
    float br[2], bz[2], bnx[2], bnh[2];
    #pragma unroll
    for (int s = 0; s < 2; ++s) {
        int j = j0 + s;
        br[s]  = b_ih[j]        + b_hh[j];
        bz[s]  = b_ih[HH + j]   + b_hh[HH + j];
        bnx[s] = b_ih[2*HH + j];
        bnh[s] = b_hh[2*HH + j];
    }

    // h = 0 (swizzled layout)
    if (tid < HH/4) {
        ((float4*)hs)[tid ^ (tid >> 3)] = make_float4(0.f, 0.f, 0.f, 0.f);
    }

    const float*  xrow = xg + (size_t)b * TT * KIN;
    const float4* hs4  = (const float4*)hs;
    const float4* xs4  = (const float4*)xs;

    // physical LDS float index of h[j0] under the swizzle
    const int g0    = j0 >> 2;
    const int hphys = ((g0 ^ (g0 >> 3)) << 2) | (j0 & 3);

    for (int t = 0; t < TT; ++t) {
        // stage x_t into LDS (coalesced float4)
        if (tid < KIN/4) {
            float4 v = ((const float4*)(xrow + (size_t)t * KIN))[tid];
            if (KIN == 256) ((float4*)xs)[tid ^ (tid >> 3)] = v;
            else            ((float4*)xs)[tid] = v;
        }
        __syncthreads();   // (1) x_t and h_{t-1} visible

        float acc[2][4];   // per unit: [r(ih+hh), z(ih+hh), n_ih, n_hh]
        #pragma unroll
        for (int s = 0; s < 2; ++s) {
            acc[s][0] = 0.f; acc[s][1] = 0.f; acc[s][2] = 0.f; acc[s][3] = 0.f;
        }

        // hidden-to-hidden partial dots
        #pragma unroll
        for (int k4 = 0; k4 < 8; ++k4) {
            float4 hv = hs4[8*q + (k4 ^ q)];
            #pragma unroll
            for (int s = 0; s < 2; ++s) {
                acc[s][0] = fmaf(whh[s][0][4*k4+0], hv.x, acc[s][0]);
                acc[s][0] = fmaf(whh[s][0][4*k4+1], hv.y, acc[s][0]);
                acc[s][0] = fmaf(whh[s][0][4*k4+2], hv.z, acc[s][0]);
                acc[s][0] = fmaf(whh[s][0][4*k4+3], hv.w, acc[s][0]);
                acc[s][1] = fmaf(whh[s][1][4*k4+0], hv.x, acc[s][1]);
                acc[s][1] = fmaf(whh[s][1][4*k4+1], hv.y, acc[s][1]);
                acc[s][1] = fmaf(whh[s][1][4*k4+2], hv.z, acc[s][1]);
                acc[s][1] = fmaf(whh[s][1][4*k4+3], hv.w, acc[s][1]);
                acc[s][3] = fmaf(whh[s][2][4*k4+0], hv.x, acc[s][3]);
                acc[s][3] = fmaf(whh[s][2][4*k4+1], hv.y, acc[s][3]);
                acc[s][3] = fmaf(whh[s][2][4*k4+2], hv.z, acc[s][3]);
                acc[s][3] = fmaf(whh[s][2][4*k4+3], hv.w, acc[s][3]);
            }
        }
        // input-to-hidden partial dots (on the fly: no gx precompute pass)
        #pragma unroll
        for (int k4 = 0; k4 < XG4; ++k4) {
            float4 xv = (KIN == 256) ? xs4[8*q + (k4 ^ q)] : xs4[2*q + k4];
            #pragma unroll
            for (int s = 0; s < 2; ++s) {
                acc[s][0] = fmaf(wih[s][0][4*k4+0], xv.x, acc[s][0]);
                acc[s][0] = fmaf(wih[s][0][4*k4+1], xv.y, acc[s][0]);
                acc[s][0] = fmaf(wih[s][0][4*k4+2], xv.z, acc[s][0]);
                acc[s][0] = fmaf(wih[s][0][4*k4+3], xv.w, acc[s][0]);
                acc[s][1] = fmaf(wih[s][1][4*k4+0], xv.x, acc[s][1]);
                acc[s][1] = fmaf(wih[s][1][4*k4+1], xv.y, acc[s][1]);
                acc[s][1] = fmaf(wih[s][1][4*k4+2], xv.z, acc[s][1]);
                acc[s][1] = fmaf(wih[s][1][4*k4+3], xv.w, acc[s][1]);
                acc[s][2] = fmaf(wih[s][2][4*k4+0], xv.x, acc[s][2]);
                acc[s][2] = fmaf(wih[s][2][4*k4+1], xv.y, acc[s][2]);
                acc[s][2] = fmaf(wih[s][2][4*k4+2], xv.z, acc[s][2]);
                acc[s][2] = fmaf(wih[s][2][4*k4+3], xv.w, acc[s][2]);
            }
        }

        // reduce over the 8 q-lanes
        #pragma unroll
        for (int s = 0; s < 2; ++s) {
            #pragma unroll
            for (int e = 0; e < 4; ++e) acc[s][e] = red8(acc[s][e]);
        }

        __syncthreads();   // (2) all reads of hs/xs done

        if (q == 0) {
            float hn0, hn1;
            {
                float r = sigf(acc[0][0] + br[0]);
                float z = sigf(acc[0][1] + bz[0]);
                float n = tanh_fast(acc[0][2] + bnx[0] + r * (acc[0][3] + bnh[0]));
                float hold = hs[hphys];
                hn0 = z * (hold - n) + n;
            }
            {
                float r = sigf(acc[1][0] + br[1]);
                float z = sigf(acc[1][1] + bz[1]);
                float n = tanh_fast(acc[1][2] + bnx[1] + r * (acc[1][3] + bnh[1]));
                float hold = hs[hphys + 1];
                hn1 = z * (hold - n) + n;
            }
            hs[hphys]     = hn0;
            hs[hphys + 1] = hn1;
            if (STORE_ALL) {
                *(float2*)(hout + ((size_t)b * TT + t) * HH + j0) = make_float2(hn0, hn1);
            } else if (t == TT - 1) {
                *(float2*)(hout + (size_t)b * HH + j0) = make_float2(hn0, hn1);
            }
        }
    }
}

// ---------- tiny MLP head: out[b] = W2 . relu(W1 h2[b] + b1) + b2 ----------
__global__ __launch_bounds__(128) void mlp_kernel(
    const float* __restrict__ h2,   // [B, 256]
    const float* __restrict__ W1,   // [128, 256]
    const float* __restrict__ b1,   // [128]
    const float* __restrict__ W2,   // [1, 128]
    const float* __restrict__ b2,   // [1]
    float* __restrict__ out)        // [B]
{
    __shared__ float hls[HH];
    __shared__ float red[128];
    const int b = blockIdx.x, tid = threadIdx.x;
    if (tid < HH/4) ((float4*)hls)[tid] = ((const float4*)(h2 + (size_t)b * HH))[tid];
    __syncthreads();
    float acc = b1[tid];
    const float4* w4 = (const float4*)(W1 + (size_t)tid * HH);
    const float4* h4 = (const float4*)hls;
    #pragma unroll 8
    for (int k = 0; k < HH/4; ++k) {
        float4 w = w4[k]; float4 h = h4[k];
        acc = fmaf(w.x, h.x, acc); acc = fmaf(w.y, h.y, acc);
        acc = fmaf(w.z, h.z, acc); acc = fmaf(w.w, h.w, acc);
    }
    red[tid] = fmaxf(acc, 0.0f) * W2[tid];
    __syncthreads();
    for (int s = 64; s > 0; s >>= 1) {
        if (tid < s) red[tid] += red[tid + s];
        __syncthreads();
    }
    if (tid == 0) out[b] = red[0] + b2[0];
}

extern "C" void kernel_launch(void* const* d_in, const int* in_sizes, int n_in,
                              void* d_out, int out_size, void* d_ws, size_t ws_size,
                              hipStream_t stream)
{
    const float* x     = (const float*)d_in[0];
    const float* W_ih0 = (const float*)d_in[1];
    const float* W_hh0 = (const float*)d_in[2];
    const float* b_ih0 = (const float*)d_in[3];
    const float* b_hh0 = (const float*)d_in[4];
    const float* W_ih1 = (const float*)d_in[5];
    const float* W_hh1 = (const float*)d_in[6];
    const float* b_ih1 = (const float*)d_in[7];
    const float* b_hh1 = (const float*)d_in[8];
    const float* W1    = (const float*)d_in[9];
    const float* b1    = (const float*)d_in[10];
    const float* W2    = (const float*)d_in[11];
    const float* b2    = (const float*)d_in[12];
    float* out = (float*)d_out;

    float* h1 = (float*)d_ws;                       // [B,T,H]  = 67.1 MB
    float* h2 = h1 + (size_t)BB * TT * HH;          // [B,H]

    gru_layer_kernel<II, true ><<<BB, 1024, 0, stream>>>(x,  W_ih0, W_hh0, b_ih0, b_hh0, h1);
    gru_layer_kernel<HH, false><<<BB, 1024, 0, stream>>>(h1, W_ih1, W_hh1, b_ih1, b_hh1, h2);
    mlp_kernel<<<BB, 128, 0, stream>>>(h2, W1, b1, W2, b2, out);
}

// Round 2
// 5617.335 us; speedup vs baseline: 6.5679x; 6.5679x over previous
//
#include <hip/hip_runtime.h>
#include <cstdint>
#include <cstddef>

typedef _Float16 h2_t __attribute__((ext_vector_type(2)));
typedef unsigned int uint;

#define BB 128
#define TT 512

// ---- ws layout (bytes) ----
// packed-f16 weight images (built by prep kernel every call)
#define OFF_PHH0   0           // 48*512*16  = 393216
#define OFF_PHH1   393216      // 393216
#define OFF_PIH0   786432      // 12*512*16  = 98304
#define OFF_PIH1L  884736      // 48*192*16  = 147456
#define OFF_PSTR   1032192     // 48*320*16  = 245760
#define OFF_BC0    1277952     // 2048
#define OFF_BC1    1280000     // 2048
#define OFF_H1G    1282048     // 128*512*128 uints = 33554432
#define OFF_H2OUT  34836480    // 128*256 fp32 = 131072
// total ~35 MB

__device__ __forceinline__ uint pack2(float a, float b){
  h2_t h; h.x = (_Float16)a; h.y = (_Float16)b;
  return __builtin_bit_cast(uint, h);
}
__device__ __forceinline__ float dot2(uint w, uint h, float acc){
  return __builtin_amdgcn_fdot2(__builtin_bit_cast(h2_t, w),
                                __builtin_bit_cast(h2_t, h), acc, false);
}
template<int CTRL>
__device__ __forceinline__ float dpp_add(float x){
  int p = __builtin_amdgcn_update_dpp(0, __float_as_int(x), CTRL, 0xF, 0xF, true);
  return x + __int_as_float(p);
}
template<int CTRL>
__device__ __forceinline__ float dpp_mov(float x){
  return __int_as_float(__builtin_amdgcn_update_dpp(0, __float_as_int(x), CTRL, 0xF, 0xF, true));
}
// sum over 8-lane groups (q = lane&7); result in all 8 lanes (verified round 1)
__device__ __forceinline__ float red8(float x){
  x = dpp_add<0xB1>(x);                                            // + lane^1
  x = dpp_add<0x4E>(x);                                            // + lane^2
  int y = __builtin_amdgcn_ds_swizzle(__float_as_int(x), 0x101F);  // lane^4
  return x + __int_as_float(y);
}
__device__ __forceinline__ float sigf(float x){ return 1.0f/(1.0f+__expf(-x)); }
__device__ __forceinline__ float tanhf_(float x){
  x = fminf(15.0f, fmaxf(-15.0f, x));
  float e = __expf(2.0f*x);
  return (e-1.0f)/(e+1.0f);
}
__device__ __forceinline__ float pick4(float a0,float a1,float a2,float a3,int s){
  float x = (s&1)? a1:a0, y = (s&1)? a3:a2;
  return (s&2)? y:x;
}
__device__ __forceinline__ void dot16(const uint4 w, const uint4 h, float& acc){
  acc = dot2(w.x,h.x,acc); acc = dot2(w.y,h.y,acc);
  acc = dot2(w.z,h.z,acc); acc = dot2(w.w,h.w,acc);
}

// =================== prep: pack fp32 weights -> per-thread f16 images ===================
// thread org of consumers: tid in [0,512): q = tid&7 (k-slice), u = tid>>3 (4 units j0=4u)
// chunk c = (g*4+s)*4 + k4 : gate g, unit-sub s, k4-th 16B (4 half2 = 8 cols of slice [32q,32q+32))
__global__ void prep_kernel(
    const float* __restrict__ W_ih0, const float* __restrict__ W_hh0,
    const float* __restrict__ b_ih0, const float* __restrict__ b_hh0,
    const float* __restrict__ W_ih1, const float* __restrict__ W_hh1,
    const float* __restrict__ b_ih1, const float* __restrict__ b_hh1,
    uint* __restrict__ PHH0, uint* __restrict__ PHH1, uint* __restrict__ PIH0,
    uint* __restrict__ PIH1L, uint* __restrict__ PSTR,
    uint* __restrict__ BC0, uint* __restrict__ BC1)
{
  int i = blockIdx.x*256 + threadIdx.x;
  if (i < 196608) {                                   // PHH0 / PHH1 (98304 uints each)
    const float* W = (i < 98304) ? W_hh0 : W_hh1;
    uint* dst = (i < 98304) ? PHH0 : PHH1;
    int j = i % 98304;
    int e = j&3, tid = (j>>2)&511, c = j>>11;
    int q = tid&7, u = tid>>3, g = c>>4, s = (c>>2)&3, k4 = c&3;
    int row = g*256 + 4*u + s, col = 32*q + 2*(k4*4+e);
    dst[(size_t)(c*512+tid)*4+e] = pack2(W[row*256+col], W[row*256+col+1]);
  } else if (i < 221184) {                            // PIH0: 12 chunks (K=64)
    int j = i - 196608;
    int e = j&3, tid = (j>>2)&511, c = j>>11;         // c in [0,12)
    int q = tid&7, u = tid>>3, g = c>>2, s = c&3;
    int row = g*256 + 4*u + s, col = 8*q + 2*e;
    PIH0[(size_t)(c*512+tid)*4+e] = pack2(W_ih0[row*64+col], W_ih0[row*64+col+1]);
  } else if (i < 258048) {                            // PIH1L: units [0,96), tid<192
    int j = i - 221184;
    int e = j&3, jj = j>>2, tau = jj%192, c = jj/192;
    int q = tau&7, u = tau>>3, g = c>>4, s = (c>>2)&3, k4 = c&3;
    int row = g*256 + 4*u + s, col = 32*q + 2*(k4*4+e);
    PIH1L[(size_t)(c*192+tau)*4+e] = pack2(W_ih1[row*256+col], W_ih1[row*256+col+1]);
  } else if (i < 319488) {                            // PSTR: units [96,256), tid in [192,512)
    int j = i - 258048;
    int e = j&3, jj = j>>2, tau = jj%320, c = jj/320;
    int tid = tau + 192;
    int q = tid&7, u = tid>>3, g = c>>4, s = (c>>2)&3, k4 = c&3;
    int row = g*256 + 4*u + s, col = 32*q + 2*(k4*4+e);
    PSTR[(size_t)(c*320+tau)*4+e] = pack2(W_ih1[row*256+col], W_ih1[row*256+col+1]);
  } else if (i < 320512) {                            // BC0/BC1: [u][4s][{(r,z),(nx,nh)}]
    int j = i - 319488;
    const float* bih = (j < 512) ? b_ih0 : b_ih1;
    const float* bhh = (j < 512) ? b_hh0 : b_hh1;
    uint* dst = (j < 512) ? BC0 : BC1;
    j &= 511;
    int u = j>>3, w = j&7, s = w>>1, jj = 4*u+s;
    uint v;
    if ((w&1)==0) v = pack2(bih[jj]+bhh[jj], bih[256+jj]+bhh[256+jj]);
    else          v = pack2(bih[512+jj],     bhh[512+jj]);
    dst[u*8+w] = v;
  }
}

// =================== layer 0: W_hh0 in RF, W_ih0 streamed from L2 ===================
__global__ __launch_bounds__(512,2) void gru_l0(
    const float* __restrict__ x,        // [B,T,64] fp32
    const uint4* __restrict__ PHH,      // [48][512]
    const uint4* __restrict__ PIH,      // [12][512]
    const uint* __restrict__ BC,        // [512]
    uint* __restrict__ h1g)             // [B,T,128] packed h2
{
  const int b = blockIdx.x, tid = threadIdx.x;
  const int q = tid & 7, u = tid >> 3;

  __shared__ __align__(16) uint hs2[128];
  __shared__ __align__(16) uint xs2[32];
  __shared__ __align__(16) uint bcl[512];

  uint4 whh[48];
  #pragma unroll
  for (int c = 0; c < 48; ++c) whh[c] = PHH[c*512 + tid];
  bcl[tid] = BC[tid];
  if (tid < 128) hs2[tid] = 0;
  float h_old[4] = {0.f,0.f,0.f,0.f};

  const float* xrow = x + (size_t)b*TT*64;
  uint* h1row = h1g + (size_t)b*TT*128;

  for (int t = 0; t < TT; ++t) {
    // prefetch ih0 stream (L2-resident, same addresses each step)
    uint4 buf[4];
    #pragma unroll
    for (int c = 0; c < 4; ++c) buf[c] = PIH[c*512 + tid];
    if (tid < 32) {
      float2 xv = ((const float2*)(xrow + t*64))[tid];
      xs2[tid] = pack2(xv.x, xv.y);
    }
    __syncthreads();

    float acc[4][4];
    #pragma unroll
    for (int s = 0; s < 4; ++s)
      #pragma unroll
      for (int c2 = 0; c2 < 4; ++c2) acc[s][c2] = 0.f;

    // hidden-to-hidden (RF weights, f16 h from LDS)
    const uint4* hs4 = (const uint4*)hs2;
    #pragma unroll
    for (int k4 = 0; k4 < 4; ++k4) {
      uint4 hv = hs4[4*q + k4];
      #pragma unroll
      for (int g = 0; g < 3; ++g) {
        const int ch = (g==2) ? 3 : g;
        #pragma unroll
        for (int s = 0; s < 4; ++s)
          dot16(whh[(g*4+s)*4+k4], hv, acc[s][ch]);
      }
    }
    // input-to-hidden: 12 streamed chunks, rolling buffer
    uint4 xv4 = ((const uint4*)xs2)[q];
    #pragma unroll
    for (int c = 0; c < 12; ++c) {
      uint4 wv = buf[c & 3];
      if (c + 4 < 12) buf[c & 3] = PIH[(c+4)*512 + tid];
      const int g = c>>2, s = c&3, ch = (g==2) ? 2 : g;
      dot16(wv, xv4, acc[s][ch]);
    }

    #pragma unroll
    for (int s = 0; s < 4; ++s)
      #pragma unroll
      for (int c2 = 0; c2 < 4; ++c2) acc[s][c2] = red8(acc[s][c2]);

    __syncthreads();   // all hs2/xs2 reads done

    // gate math, lane-split: lane handles unit sub-index sl = q&3
    const int sl = q & 3;
    float R  = pick4(acc[0][0],acc[1][0],acc[2][0],acc[3][0],sl);
    float Z  = pick4(acc[0][1],acc[1][1],acc[2][1],acc[3][1],sl);
    float NX = pick4(acc[0][2],acc[1][2],acc[2][2],acc[3][2],sl);
    float NH = pick4(acc[0][3],acc[1][3],acc[2][3],acc[3][3],sl);
    uint2 bv = ((const uint2*)bcl)[u*4 + sl];
    h2_t b01 = __builtin_bit_cast(h2_t, bv.x);
    h2_t b23 = __builtin_bit_cast(h2_t, bv.y);
    float r = sigf(R + (float)b01.x);
    float z = sigf(Z + (float)b01.y);
    float n = tanhf_(NX + (float)b23.x + r*(NH + (float)b23.y));
    float hp = pick4(h_old[0],h_old[1],h_old[2],h_old[3],sl);
    float hn = z*(hp - n) + n;
    h_old[0] = dpp_mov<0x00>(hn);
    h_old[1] = dpp_mov<0x55>(hn);
    h_old[2] = dpp_mov<0xAA>(hn);
    h_old[3] = dpp_mov<0xFF>(hn);
    if (q == 0) {
      uint2 hw;
      hw.x = pack2(h_old[0], h_old[1]);
      hw.y = pack2(h_old[2], h_old[3]);
      ((uint2*)hs2)[u] = hw;
      ((uint2*)(h1row + t*128))[u] = hw;
    }
  }
}

// ============ layer 1: W_hh1 RF; W_ih1 units[0,96) in LDS, units[96,256) L2-stream ============
__global__ __launch_bounds__(512,2) void gru_l1(
    const uint* __restrict__ h1g,       // [B,T,128] packed h2
    const uint4* __restrict__ PHH,      // [48][512]
    const uint4* __restrict__ PLDS,     // [48][192]
    const uint4* __restrict__ PSTRp,    // [48][320]
    const uint* __restrict__ BC,
    float* __restrict__ h2out)          // [B,256] fp32
{
  extern __shared__ uint4 ldsw[];       // [192][49] (48 chunks + 1 pad for banks)
  __shared__ __align__(16) uint hs2[128];
  __shared__ __align__(16) uint xs2[128];
  __shared__ __align__(16) uint bcl[512];

  const int b = blockIdx.x, tid = threadIdx.x;
  const int q = tid & 7, u = tid >> 3;
  const bool strm = (tid >= 192);       // wave-uniform (waves 3..7)

  uint4 whh[48];
  #pragma unroll
  for (int c = 0; c < 48; ++c) whh[c] = PHH[c*512 + tid];
  if (tid < 192) {
    for (int c = 0; c < 48; ++c) ldsw[tid*49 + c] = PLDS[c*192 + tid];
  }
  bcl[tid] = BC[tid];
  if (tid < 128) hs2[tid] = 0;
  float h_old[4] = {0.f,0.f,0.f,0.f};

  const uint* xrow = h1g + (size_t)b*TT*128;
  const uint4* ps = PSTRp + (strm ? (tid - 192) : 0);

  for (int t = 0; t < TT; ++t) {
    uint4 buf[5];
    if (strm) {
      #pragma unroll
      for (int c = 0; c < 5; ++c) buf[c] = ps[c*320];
    }
    if (tid < 128) xs2[tid] = xrow[t*128 + tid];
    __syncthreads();

    float acc[4][4];
    #pragma unroll
    for (int s = 0; s < 4; ++s)
      #pragma unroll
      for (int c2 = 0; c2 < 4; ++c2) acc[s][c2] = 0.f;

    const uint4* hs4 = (const uint4*)hs2;
    const uint4* xs4 = (const uint4*)xs2;

    // hidden-to-hidden (RF)
    #pragma unroll
    for (int k4 = 0; k4 < 4; ++k4) {
      uint4 hv = hs4[4*q + k4];
      #pragma unroll
      for (int g = 0; g < 3; ++g) {
        const int ch = (g==2) ? 3 : g;
        #pragma unroll
        for (int s = 0; s < 4; ++s)
          dot16(whh[(g*4+s)*4+k4], hv, acc[s][ch]);
      }
    }
    // input-to-hidden
    if (!strm) {
      #pragma unroll
      for (int k4 = 0; k4 < 4; ++k4) {
        uint4 xv = xs4[4*q + k4];
        #pragma unroll
        for (int g = 0; g < 3; ++g) {
          const int ch = (g==2) ? 2 : g;
          #pragma unroll
          for (int s = 0; s < 4; ++s)
            dot16(ldsw[tid*49 + (g*4+s)*4+k4], xv, acc[s][ch]);
        }
      }
    } else {
      #pragma unroll
      for (int c = 0; c < 48; ++c) {
        uint4 wv = buf[c % 5];
        if (c + 5 < 48) buf[c % 5] = ps[(c+5)*320];
        const int k4 = c&3, s = (c>>2)&3, g = c>>4, ch = (g==2) ? 2 : g;
        uint4 xv = xs4[4*q + k4];
        dot16(wv, xv, acc[s][ch]);
      }
    }

    #pragma unroll
    for (int s = 0; s < 4; ++s)
      #pragma unroll
      for (int c2 = 0; c2 < 4; ++c2) acc[s][c2] = red8(acc[s][c2]);

    __syncthreads();

    const int sl = q & 3;
    float R  = pick4(acc[0][0],acc[1][0],acc[2][0],acc[3][0],sl);
    float Z  = pick4(acc[0][1],acc[1][1],acc[2][1],acc[3][1],sl);
    float NX = pick4(acc[0][2],acc[1][2],acc[2][2],acc[3][2],sl);
    float NH = pick4(acc[0][3],acc[1][3],acc[2][3],acc[3][3],sl);
    uint2 bv = ((const uint2*)bcl)[u*4 + sl];
    h2_t b01 = __builtin_bit_cast(h2_t, bv.x);
    h2_t b23 = __builtin_bit_cast(h2_t, bv.y);
    float r = sigf(R + (float)b01.x);
    float z = sigf(Z + (float)b01.y);
    float n = tanhf_(NX + (float)b23.x + r*(NH + (float)b23.y));
    float hp = pick4(h_old[0],h_old[1],h_old[2],h_old[3],sl);
    float hn = z*(hp - n) + n;
    h_old[0] = dpp_mov<0x00>(hn);
    h_old[1] = dpp_mov<0x55>(hn);
    h_old[2] = dpp_mov<0xAA>(hn);
    h_old[3] = dpp_mov<0xFF>(hn);
    if (q == 0) {
      uint2 hw;
      hw.x = pack2(h_old[0], h_old[1]);
      hw.y = pack2(h_old[2], h_old[3]);
      ((uint2*)hs2)[u] = hw;
      if (t == TT-1)
        ((float4*)(h2out + b*256))[u] = make_float4(h_old[0],h_old[1],h_old[2],h_old[3]);
    }
  }
}

// =================== MLP head (unchanged from round 1) ===================
__global__ __launch_bounds__(128) void mlp_kernel(
    const float* __restrict__ h2, const float* __restrict__ W1,
    const float* __restrict__ b1, const float* __restrict__ W2,
    const float* __restrict__ b2, float* __restrict__ out)
{
  __shared__ float hls[256];
  __shared__ float red[128];
  const int b = blockIdx.x, tid = threadIdx.x;
  if (tid < 64) ((float4*)hls)[tid] = ((const float4*)(h2 + (size_t)b*256))[tid];
  __syncthreads();
  float acc = b1[tid];
  const float4* w4 = (const float4*)(W1 + (size_t)tid*256);
  const float4* h4 = (const float4*)hls;
  #pragma unroll 8
  for (int k = 0; k < 64; ++k) {
    float4 w = w4[k]; float4 h = h4[k];
    acc = fmaf(w.x,h.x,acc); acc = fmaf(w.y,h.y,acc);
    acc = fmaf(w.z,h.z,acc); acc = fmaf(w.w,h.w,acc);
  }
  red[tid] = fmaxf(acc, 0.0f) * W2[tid];
  __syncthreads();
  for (int s = 64; s > 0; s >>= 1) {
    if (tid < s) red[tid] += red[tid + s];
    __syncthreads();
  }
  if (tid == 0) out[b] = red[0] + b2[0];
}

extern "C" void kernel_launch(void* const* d_in, const int* in_sizes, int n_in,
                              void* d_out, int out_size, void* d_ws, size_t ws_size,
                              hipStream_t stream)
{
  const float* x     = (const float*)d_in[0];
  const float* W_ih0 = (const float*)d_in[1];
  const float* W_hh0 = (const float*)d_in[2];
  const float* b_ih0 = (const float*)d_in[3];
  const float* b_hh0 = (const float*)d_in[4];
  const float* W_ih1 = (const float*)d_in[5];
  const float* W_hh1 = (const float*)d_in[6];
  const float* b_ih1 = (const float*)d_in[7];
  const float* b_hh1 = (const float*)d_in[8];
  const float* W1    = (const float*)d_in[9];
  const float* b1    = (const float*)d_in[10];
  const float* W2    = (const float*)d_in[11];
  const float* b2    = (const float*)d_in[12];

  char* ws = (char*)d_ws;
  uint* PHH0  = (uint*)(ws + OFF_PHH0);
  uint* PHH1  = (uint*)(ws + OFF_PHH1);
  uint* PIH0  = (uint*)(ws + OFF_PIH0);
  uint* PIH1L = (uint*)(ws + OFF_PIH1L);
  uint* PSTR  = (uint*)(ws + OFF_PSTR);
  uint* BC0   = (uint*)(ws + OFF_BC0);
  uint* BC1   = (uint*)(ws + OFF_BC1);
  uint* H1G   = (uint*)(ws + OFF_H1G);
  float* H2O  = (float*)(ws + OFF_H2OUT);

  const int l1_dyn_lds = 192*49*16;   // 150528 B
  (void)hipFuncSetAttribute(reinterpret_cast<const void*>(gru_l1),
                            hipFuncAttributeMaxDynamicSharedMemorySize, l1_dyn_lds);

  prep_kernel<<<1252, 256, 0, stream>>>(W_ih0, W_hh0, b_ih0, b_hh0,
                                        W_ih1, W_hh1, b_ih1, b_hh1,
                                        PHH0, PHH1, PIH0, PIH1L, PSTR, BC0, BC1);
  gru_l0<<<BB, 512, 0, stream>>>(x, (const uint4*)PHH0, (const uint4*)PIH0, BC0, H1G);
  gru_l1<<<BB, 512, l1_dyn_lds, stream>>>(H1G, (const uint4*)PHH1, (const uint4*)PIH1L,
                                          (const uint4*)PSTR, BC1, H2O);
  mlp_kernel<<<BB, 128, 0, stream>>>(H2O, W1, b1, W2, b2, (float*)d_out);
}